// Round 4
// baseline (742.107 us; speedup 1.0000x reference)
//
#include <hip/hip_runtime.h>
#include <math.h>

#define NB 8
#define NN 2048
#define SCALE 20.0f   // 1 / 0.05
#define RPW 4                // rows per wave (fused path)
#define CH  (NN / RPW)       // 512 chunks per matrix

typedef float v4f __attribute__((ext_vector_type(4)));

__device__ __forceinline__ float wave_max(float x) {
#pragma unroll
    for (int off = 32; off >= 1; off >>= 1)
        x = fmaxf(x, __shfl_xor(x, off, 64));
    return x;
}
__device__ __forceinline__ float wave_sum(float x) {
#pragma unroll
    for (int off = 32; off >= 1; off >>= 1)
        x += __shfl_xor(x, off, 64);
    return x;
}

// ---------------- fused path ----------------
// One wave owns RPW rows (no cross-wave coupling, no barriers).
// Per row: u[row] = LSE_c(A*20 - v); column partial s[c] += exp(x - u_row)
// = e[c]/S. Per-wave partials -> ps[wg][col] (nontemporal: keep A in L3).
__global__ __launch_bounds__(256, 4) void fused_iter(const float* __restrict__ A,
                                                     const float* __restrict__ v,
                                                     float* __restrict__ u,
                                                     float* __restrict__ ps) {
    const int w     = threadIdx.x >> 6;
    const int lane  = threadIdx.x & 63;
    const int wg    = blockIdx.x * 4 + w;        // 0 .. NB*CH-1
    const int b     = wg >> 9;                   // / CH
    const int chunk = wg & (CH - 1);
    const int row0  = chunk * RPW;

    const float4* v4 = (const float4*)(v + (size_t)b * NN);
    float vv[32];
#pragma unroll
    for (int k = 0; k < 8; ++k) {
        float4 t = v4[lane + (k << 6)];
        vv[4 * k + 0] = t.x; vv[4 * k + 1] = t.y;
        vv[4 * k + 2] = t.z; vv[4 * k + 3] = t.w;
    }

    float s[32];
#pragma unroll
    for (int i = 0; i < 32; ++i) s[i] = 0.f;

#pragma unroll
    for (int r = 0; r < RPW; ++r) {
        const float4* a4 = (const float4*)(A + ((size_t)b * NN + row0 + r) * NN);
        float x[32];
#pragma unroll
        for (int k = 0; k < 8; ++k) {
            float4 t = a4[lane + (k << 6)];
            x[4 * k + 0] = fmaf(t.x, SCALE, -vv[4 * k + 0]);
            x[4 * k + 1] = fmaf(t.y, SCALE, -vv[4 * k + 1]);
            x[4 * k + 2] = fmaf(t.z, SCALE, -vv[4 * k + 2]);
            x[4 * k + 3] = fmaf(t.w, SCALE, -vv[4 * k + 3]);
        }
        float m = x[0];
#pragma unroll
        for (int i = 1; i < 32; ++i) m = fmaxf(m, x[i]);
        m = wave_max(m);
        float ls = 0.f;
#pragma unroll
        for (int i = 0; i < 32; ++i) { x[i] = __expf(x[i] - m); ls += x[i]; }
        float S = wave_sum(ls);
        if (lane == 0) u[b * NN + row0 + r] = m + __logf(S);
        float rS = __builtin_amdgcn_rcpf(S);
#pragma unroll
        for (int i = 0; i < 32; ++i) s[i] = fmaf(x[i], rS, s[i]);
    }

    v4f* pb = (v4f*)(ps + (size_t)wg * NN);
#pragma unroll
    for (int k = 0; k < 8; ++k) {
        v4f o = {s[4 * k], s[4 * k + 1], s[4 * k + 2], s[4 * k + 3]};
        __builtin_nontemporal_store(o, pb + lane + (k << 6));
    }
}

// v[c] += log( sum over CH chunks of ps[b][chunk][c] ).
// 512 blocks; block = 32 cols x 8 chunk-groups (64 chunks each); LDS combine.
__global__ __launch_bounds__(256) void combine(const float* __restrict__ ps,
                                               float* __restrict__ v) {
    const int coll = threadIdx.x & 31;
    const int grp  = threadIdx.x >> 5;           // 0..7
    const int gcol = blockIdx.x * 32 + coll;     // 0 .. NB*NN-1
    const int b    = gcol >> 11;
    const int col  = gcol & (NN - 1);
    const float* pb = ps + (size_t)b * CH * NN + col + (size_t)grp * (CH / 8) * NN;

    float s0 = 0.f, s1 = 0.f, s2 = 0.f, s3 = 0.f;
#pragma unroll 4
    for (int i = 0; i < CH / 8; i += 4) {
        s0 += __builtin_nontemporal_load(pb + (size_t)(i + 0) * NN);
        s1 += __builtin_nontemporal_load(pb + (size_t)(i + 1) * NN);
        s2 += __builtin_nontemporal_load(pb + (size_t)(i + 2) * NN);
        s3 += __builtin_nontemporal_load(pb + (size_t)(i + 3) * NN);
    }
    __shared__ float sm[8][33];
    sm[grp][coll] = (s0 + s1) + (s2 + s3);
    __syncthreads();
    if (threadIdx.x < 32) {
        float t = 0.f;
#pragma unroll
        for (int g = 0; g < 8; ++g) t += sm[g][threadIdx.x];
        v[gcol] += __logf(t);
    }
}

// ---------------- fallback path ----------------
__global__ __launch_bounds__(256) void row_lse(const float* __restrict__ A,
                                               const float* __restrict__ v,
                                               float* __restrict__ u) {
    const int wid  = threadIdx.x >> 6;
    const int lane = threadIdx.x & 63;
    const int row  = blockIdx.x * 4 + wid;
    const int b    = row >> 11;
    const float4* a4 = (const float4*)(A + (size_t)row * NN);
    const float4* v4 = (const float4*)(v + (size_t)b * NN);
    float x[32];
#pragma unroll
    for (int k = 0; k < 8; ++k) {
        float4 a  = a4[lane + (k << 6)];
        float4 vv = v4[lane + (k << 6)];
        x[4 * k + 0] = fmaf(a.x, SCALE, -vv.x);
        x[4 * k + 1] = fmaf(a.y, SCALE, -vv.y);
        x[4 * k + 2] = fmaf(a.z, SCALE, -vv.z);
        x[4 * k + 3] = fmaf(a.w, SCALE, -vv.w);
    }
    float m = -INFINITY;
#pragma unroll
    for (int i = 0; i < 32; ++i) m = fmaxf(m, x[i]);
    m = wave_max(m);
    float s = 0.f;
#pragma unroll
    for (int i = 0; i < 32; ++i) s += __expf(x[i] - m);
    s = wave_sum(s);
    if (lane == 0) u[row] = m + __logf(s);
}

__global__ __launch_bounds__(256) void col_lse(const float* __restrict__ A,
                                               const float* __restrict__ u,
                                               float* __restrict__ v) {
    const int b    = blockIdx.x >> 6;
    const int tile = blockIdx.x & 63;
    const int ci   = threadIdx.x & 31;
    const int rg   = threadIdx.x >> 5;
    const int col  = (tile << 5) + ci;
    const float* Ab = A + (size_t)b * NN * NN;
    const float* ub = u + b * NN;
    float m0 = -INFINITY, s0 = 0.f, m1 = -INFINITY, s1 = 0.f;
    for (int r = rg; r < NN; r += 16) {
        float x0 = fmaf(Ab[(size_t)r * NN + col], SCALE, -ub[r]);
        float x1 = fmaf(Ab[(size_t)(r + 8) * NN + col], SCALE, -ub[r + 8]);
        float nm0 = fmaxf(m0, x0);
        s0 = s0 * __expf(m0 - nm0) + __expf(x0 - nm0); m0 = nm0;
        float nm1 = fmaxf(m1, x1);
        s1 = s1 * __expf(m1 - nm1) + __expf(x1 - nm1); m1 = nm1;
    }
    float m = fmaxf(m0, m1);
    float s = s0 * __expf(m0 - m) + s1 * __expf(m1 - m);
    __shared__ float sm[8][33];
    __shared__ float ss[8][33];
    sm[rg][ci] = m; ss[rg][ci] = s;
    __syncthreads();
    if (threadIdx.x < 32) {
        const int c = threadIdx.x;
        float M = sm[0][c], S = ss[0][c];
#pragma unroll
        for (int g = 1; g < 8; ++g) {
            float mg = sm[g][c], sg = ss[g][c];
            float nM = fmaxf(M, mg);
            S = S * __expf(M - nM) + sg * __expf(mg - nM);
            M = nM;
        }
        v[b * NN + (tile << 5) + c] = M + __logf(S);
    }
}

// ---------------- final ----------------
__global__ __launch_bounds__(256) void final_exp(const float* __restrict__ A,
                                                 const float* __restrict__ u,
                                                 const float* __restrict__ v,
                                                 float* __restrict__ out) {
    const int i4    = blockIdx.x * 256 + threadIdx.x;
    const int rglob = i4 >> 9;
    const int c4    = i4 & 511;
    const int b     = rglob >> 11;
    const float uu  = u[rglob];
    float4 a  = ((const float4*)A)[i4];
    float4 vv = ((const float4*)(v + (size_t)b * NN))[c4];
    v4f o;
    o.x = __expf(fmaf(a.x, SCALE, -uu) - vv.x);
    o.y = __expf(fmaf(a.y, SCALE, -uu) - vv.y);
    o.z = __expf(fmaf(a.z, SCALE, -uu) - vv.z);
    o.w = __expf(fmaf(a.w, SCALE, -uu) - vv.w);
    __builtin_nontemporal_store(o, (v4f*)out + i4);
}

extern "C" void kernel_launch(void* const* d_in, const int* in_sizes, int n_in,
                              void* d_out, int out_size, void* d_ws, size_t ws_size,
                              hipStream_t stream) {
    const float* A = (const float*)d_in[0];
    float* out = (float*)d_out;
    float* u  = (float*)d_ws;                 // NB*NN floats
    float* v  = u + NB * NN;                  // NB*NN floats
    float* ps = v + NB * NN;                  // NB*CH*NN floats (fused path)

    const size_t need = ((size_t)2 * NB * NN + (size_t)NB * CH * NN) * sizeof(float);

    hipMemsetAsync(v, 0, NB * NN * sizeof(float), stream);

    if (ws_size >= need) {
        for (int it = 0; it < 10; ++it) {
            fused_iter<<<NB * CH / 4, 256, 0, stream>>>(A, v, u, ps);
            combine<<<NB * NN / 32, 256, 0, stream>>>(ps, v);
        }
    } else {
        for (int it = 0; it < 10; ++it) {
            row_lse<<<NB * NN / 4, 256, 0, stream>>>(A, v, u);
            col_lse<<<NB * (NN / 32), 256, 0, stream>>>(A, u, v);
        }
    }
    final_exp<<<NB * NN * NN / 1024, 256, 0, stream>>>(A, u, v, out);
}